// Round 3
// baseline (763.658 us; speedup 1.0000x reference)
//
#include <hip/hip_runtime.h>
#include <math.h>

#define TRIALS 4096
#define STEPS  8192
#define ORDER  3
#define GEN    (STEPS - ORDER)   // 8189 generated steps per trial
#define NCHUNK 32
#define CLEN   256               // output steps per chunk (NCHUNK*CLEN == STEPS)

// ---------------- Pass A: zero-init chunk scan -> tail state v_c ----------------
__global__ __launch_bounds__(256) void pass_scan(
    const float2* __restrict__ normals,       // (TRIALS, GEN, 2) fp32
    const float* __restrict__ alpha,          // (3,2)
    const float* __restrict__ sigma,          // (2,)
    const float* __restrict__ rho_p,          // (1,)
    const float* __restrict__ mu,             // (2,)
    float* __restrict__ ws_v)                 // (TRIALS, NCHUNK, 6)
{
    int tid   = blockIdx.x * 256 + threadIdx.x;
    int trial = tid >> 5;
    int c     = tid & 31;

    float a00 = alpha[0], a01 = alpha[1];
    float a10 = alpha[2], a11 = alpha[3];
    float a20 = alpha[4], a21 = alpha[5];
    float r   = rho_p[0];
    float c00 = sigma[0];
    float c10 = r * sigma[1];
    float c11 = sqrtf(1.0f - r * r) * sigma[1];
    float m0  = mu[0], m1 = mu[1];

    int gs = c * CLEN - ORDER;
    int n  = CLEN;
    if (c == 0) { gs = 0; n = CLEN - ORDER; }

    const float2* p = normals + (size_t)trial * GEN + gs;

    float x1 = 0.f, x2 = 0.f, x3 = 0.f;   // dim0 state, x1 newest
    float y1 = 0.f, y2 = 0.f, y3 = 0.f;   // dim1
    #pragma unroll 4
    for (int i = 0; i < n; ++i) {
        float2 u = p[i];
        float w0 = fmaf(u.x, c00, m0);
        float w1 = fmaf(u.y, c11, fmaf(u.x, c10, m1));
        float nx = fmaf(a20, x1, fmaf(a10, x2, fmaf(a00, x3, w0)));
        x3 = x2; x2 = x1; x1 = nx;
        float ny = fmaf(a21, y1, fmaf(a11, y2, fmaf(a01, y3, w1)));
        y3 = y2; y2 = y1; y1 = ny;
    }
    float* v = ws_v + (size_t)tid * 6;
    v[0] = x1; v[1] = x2; v[2] = x3;
    v[3] = y1; v[4] = y2; v[5] = y3;
}

// ---------------- Pass B: affine combine (in-place v -> incoming state) --------
__global__ __launch_bounds__(256) void pass_combine(
    const float* __restrict__ alpha,
    const float* __restrict__ xmu_p,
    const float* __restrict__ x0p,            // (TRIALS, 3, 2)
    float* __restrict__ ws)
{
    int tid   = blockIdx.x * 256 + threadIdx.x;   // 8192 = TRIALS*2
    if (tid >= TRIALS * 2) return;
    int trial = tid >> 1;
    int d     = tid & 1;

    float a0 = alpha[0 * 2 + d];   // coef of oldest lag
    float a1 = alpha[1 * 2 + d];
    float a2 = alpha[2 * 2 + d];   // coef of newest lag
    float xm = xmu_p[d];

    // initial lag window: carry[0]=oldest -> x3, carry[2]=newest -> x1
    float x1 = x0p[(trial * 3 + 2) * 2 + d] - xm;
    float x2 = x0p[(trial * 3 + 1) * 2 + d] - xm;
    float x3 = x0p[(trial * 3 + 0) * 2 + d] - xm;

    float* w = ws + (size_t)trial * (NCHUNK * 6) + d * 3;

    // chunk 0 runs CLEN-ORDER noisy steps: s_in[1] = A^(CLEN-3) * s0 + v_0
    float v0 = w[0], v1 = w[1], v2 = w[2];
    w[0] = x1; w[1] = x2; w[2] = x3;
    for (int i = 0; i < CLEN - ORDER; ++i) {
        float nx = fmaf(a2, x1, fmaf(a1, x2, a0 * x3));
        x3 = x2; x2 = x1; x1 = nx;
    }
    x1 += v0; x2 += v1; x3 += v2;

    // M = A^CLEN via basis-vector evolution
    float m00 = 1.f, m10 = 0.f, m20 = 0.f;
    float m01 = 0.f, m11 = 1.f, m21 = 0.f;
    float m02 = 0.f, m12 = 0.f, m22 = 1.f;
    for (int i = 0; i < CLEN; ++i) {
        float t0 = fmaf(a2, m00, fmaf(a1, m10, a0 * m20));
        float t1 = fmaf(a2, m01, fmaf(a1, m11, a0 * m21));
        float t2 = fmaf(a2, m02, fmaf(a1, m12, a0 * m22));
        m20 = m10; m10 = m00; m00 = t0;
        m21 = m11; m11 = m01; m01 = t1;
        m22 = m12; m12 = m02; m02 = t2;
    }

    for (int c = 1; c < NCHUNK; ++c) {
        float* wc = w + c * 6;
        float u0 = wc[0], u1 = wc[1], u2 = wc[2];
        wc[0] = x1; wc[1] = x2; wc[2] = x3;
        float nx1 = m00 * x1 + m01 * x2 + m02 * x3 + u0;
        float nx2 = m10 * x1 + m11 * x2 + m12 * x3 + u1;
        float nx3 = m20 * x1 + m21 * x2 + m22 * x3 + u2;
        x1 = nx1; x2 = nx2; x3 = nx3;
    }
}

// ---------------- Pass C: emit fp32 outputs from true incoming states ----------
__global__ __launch_bounds__(256) void pass_emit(
    const float2* __restrict__ normals,
    const float* __restrict__ alpha,
    const float* __restrict__ xmu_p,
    const float* __restrict__ sigma,
    const float* __restrict__ rho_p,
    const float* __restrict__ mu,
    const float* __restrict__ x0p,
    const float* __restrict__ ws,
    float2* __restrict__ out2)                // (TRIALS, STEPS, 2) fp32
{
    int tid   = blockIdx.x * 256 + threadIdx.x;
    int trial = tid >> 5;
    int c     = tid & 31;

    float a00 = alpha[0], a01 = alpha[1];
    float a10 = alpha[2], a11 = alpha[3];
    float a20 = alpha[4], a21 = alpha[5];
    float r   = rho_p[0];
    float c00 = sigma[0];
    float c10 = r * sigma[1];
    float c11 = sqrtf(1.0f - r * r) * sigma[1];
    float m0  = mu[0], m1 = mu[1];
    float xm0 = xmu_p[0], xm1 = xmu_p[1];

    const float* s = ws + (size_t)tid * 6;
    float x1 = s[0], x2 = s[1], x3 = s[2];
    float y1 = s[3], y2 = s[4], y3 = s[5];

    int gs = c * CLEN - ORDER;
    int n  = CLEN;
    float2* op = out2 + (size_t)trial * STEPS + c * CLEN;
    if (c == 0) {
        gs = 0; n = CLEN - ORDER;
        // first ORDER rows: (x_0 - xmu) + xmu, matching reference arithmetic
        #pragma unroll
        for (int k = 0; k < ORDER; ++k) {
            float v0 = (x0p[(trial * 3 + k) * 2 + 0] - xm0) + xm0;
            float v1 = (x0p[(trial * 3 + k) * 2 + 1] - xm1) + xm1;
            op[k] = make_float2(v0, v1);
        }
        op += ORDER;
    }
    const float2* p = normals + (size_t)trial * GEN + gs;

    #pragma unroll 4
    for (int i = 0; i < n; ++i) {
        float2 u = p[i];
        float w0 = fmaf(u.x, c00, m0);
        float w1 = fmaf(u.y, c11, fmaf(u.x, c10, m1));
        float nx = fmaf(a20, x1, fmaf(a10, x2, fmaf(a00, x3, w0)));
        x3 = x2; x2 = x1; x1 = nx;
        float ny = fmaf(a21, y1, fmaf(a11, y2, fmaf(a01, y3, w1)));
        y3 = y2; y2 = y1; y1 = ny;
        op[i] = make_float2(nx + xm0, ny + xm1);
    }
}

extern "C" void kernel_launch(void* const* d_in, const int* in_sizes, int n_in,
                              void* d_out, int out_size, void* d_ws, size_t ws_size,
                              hipStream_t stream) {
    const float*  alpha = (const float*)d_in[0];
    const float*  xmu   = (const float*)d_in[1];
    const float*  sigma = (const float*)d_in[2];
    const float*  rho   = (const float*)d_in[3];
    const float*  mu    = (const float*)d_in[4];
    const float*  x0    = (const float*)d_in[5];
    const float2* norm2 = (const float2*)d_in[6];
    float2*       out2  = (float2*)d_out;
    float*        ws    = (float*)d_ws;   // needs TRIALS*NCHUNK*6*4 = 3 MiB

    int threadsA = TRIALS * NCHUNK;              // 131072
    hipLaunchKernelGGL(pass_scan, dim3(threadsA / 256), dim3(256), 0, stream,
                       norm2, alpha, sigma, rho, mu, ws);

    int threadsB = TRIALS * 2;                   // 8192
    hipLaunchKernelGGL(pass_combine, dim3(threadsB / 256), dim3(256), 0, stream,
                       alpha, xmu, x0, ws);

    hipLaunchKernelGGL(pass_emit, dim3(threadsA / 256), dim3(256), 0, stream,
                       norm2, alpha, xmu, sigma, rho, mu, x0, ws, out2);
}